// Round 11
// baseline (471.515 us; speedup 1.0000x reference)
//
#include <hip/hip_runtime.h>
#include <hip/hip_bf16.h>
#include <math.h>

// Problem constants
#define H   512
#define E   512
#define B_  256
#define T_  64
#define G4  2048   // 4*H
#define C1  256    // MLP hidden
#define BT  16384  // B*T

#define SPIN_CAP (1 << 22)   // discovery spin bound (dispatch latency)
#define POLL_CAP (1 << 18)   // per-step poll bound: failure -> slow-but-correct

typedef __attribute__((ext_vector_type(8))) short  short8;   // 8 bf16 (4 VGPRs)
typedef __attribute__((ext_vector_type(4))) float  f32x4;    // MFMA acc
typedef __attribute__((ext_vector_type(4))) int    i32x4;    // 16B granule
typedef __attribute__((ext_vector_type(4))) unsigned short ushort4v;
typedef unsigned short ushort;
typedef unsigned long long u64;

// LDS tile: row-major [row][kc granule], pitch 65 granules (odd) = 520 ushorts.
#define PITCH_US 520

#define BAR_LGKM() asm volatile("s_waitcnt lgkmcnt(0)\n\ts_barrier" ::: "memory")
#define BAR_ALL()  asm volatile("s_waitcnt vmcnt(0) lgkmcnt(0)\n\ts_barrier" ::: "memory")

// ---------------------------------------------------------------------------
// Design ledger (R0-R10, measured on MI355X):
//   - Cross-CU flags MUST go through the MALL (AGENT both sides). Local-L2
//     signaling impossible (R2/R3/R4). Streamed data lines work plain->sc0.
//   - Sync chain fully bracketed: poll contention (R5), RMW convoy (R9),
//     per-wave dataflow (R7) all null/negative. Block-lockstep + LDS staging
//     + 2 waves/SIMD (R8, 247us) is the local optimum; lstm step ~3.9us is
//     a stacked-latency floor. lstm FROZEN in R8/R9 form.
//   - gemm_score n-fold (R10) REGRESSED (parallelism-bound, not MALL-bound):
//     grid (4,128) + atomicAdd is the proven form. Reverted.
//   - R11 (this): kernel-count attack. 7 launches -> 3: prep_all fuses
//     {weight-prep || embed-gather || init || sync-zero} (independent,
//     previously stream-serialized); gemm_score absorbs reduce_scores via
//     atomicAdd into out[b] (out pre-seeded with T*b2 in prep_all).
// ---------------------------------------------------------------------------

__device__ __forceinline__ ushort f2bf(float x) {
    unsigned u = __builtin_bit_cast(unsigned, x);
    unsigned r = (u + 0x7FFFu + ((u >> 16) & 1u)) >> 16;
    return (ushort)r;
}
__device__ __forceinline__ float fast_sig(float x) {
    return __builtin_amdgcn_rcpf(1.f + __expf(-x));
}
__device__ __forceinline__ float fast_tanh(float x) {
    return 1.f - 2.f * __builtin_amdgcn_rcpf(1.f + __expf(2.f * x));
}

// 2x 16B loads, batched, drained. sc0: L1-bypass, local XCD L2 (R8-proven).
#define LOAD2_SC0(v0,v1,p0,p1) \
  asm volatile("global_load_dwordx4 %0, %2, off sc0\n\t" \
               "global_load_dwordx4 %1, %3, off sc0\n\t" \
               "s_waitcnt vmcnt(0)" \
               : "=&v"(v0), "=&v"(v1) : "v"(p0), "v"(p1) : "memory")
#define LOAD2_SC01(v0,v1,p0,p1) \
  asm volatile("global_load_dwordx4 %0, %2, off sc0 sc1\n\t" \
               "global_load_dwordx4 %1, %3, off sc0 sc1\n\t" \
               "s_waitcnt vmcnt(0)" \
               : "=&v"(v0), "=&v"(v1) : "v"(p0), "v"(p1) : "memory")

// ---------------------------------------------------------------------------
// P*: fused prep — ONE launch, grid-partitioned, all sections independent:
//   [0, 2304)          weight transpose+cast fp32 [K][N] -> bf16 [N][K]
//   [2304, 10496)      embed gather: 2 rows/block (128 thr each half)
//   [10496, 10624)     init_prep: 2 rows/block
//   [10624, 10642)     out[b] = T*b2 seed + zero xcd_tbl/cnts
// ---------------------------------------------------------------------------
#define PREP_N  2304
#define GATH_B  (PREP_N)
#define GATH_N  (BT / 2)
#define INIT_B  (GATH_B + GATH_N)
#define INIT_N  (B_ / 2)
#define ZERO_B  (INIT_B + INIT_N)
#define ZERO_N  18
#define PALL_N  (ZERO_B + ZERO_N)

__global__ __launch_bounds__(256) void prep_all(
    const float* __restrict__ Wx, const float* __restrict__ Wh,
    const float* __restrict__ W1,
    ushort* __restrict__ WxT, ushort* __restrict__ WhT, ushort* __restrict__ W1T,
    const float* __restrict__ emb, const int* __restrict__ idx,
    ushort* __restrict__ X,
    const float* __restrict__ init, ushort* __restrict__ h0,
    ushort* __restrict__ S,
    float* __restrict__ out, const float* __restrict__ b2,
    int* __restrict__ sync_ints)
{
    const int tid = threadIdx.x;
    int bx = blockIdx.x;

    if (bx < PREP_N) {
        // ---- weight transpose + cast ----
        __shared__ float t[32][33];
        const float* in; ushort* outp; int K, N, k0, n0;
        if (bx < 1024)       { in = Wx; outp = WxT; K = 512;  N = 2048; k0 = (bx >> 6) * 32; n0 = (bx & 63) * 32; }
        else if (bx < 2048)  { bx -= 1024; in = Wh; outp = WhT; K = 512;  N = 2048; k0 = (bx >> 6) * 32; n0 = (bx & 63) * 32; }
        else                 { bx -= 2048; in = W1; outp = W1T; K = 1024; N = 256;  k0 = (bx >> 3) * 32; n0 = (bx & 7) * 32; }
        const int tr = tid >> 3;
        const int tc = (tid & 7) * 4;
        float4 v = *(const float4*)(in + (size_t)(k0 + tr) * N + n0 + tc);
        t[tr][tc + 0] = v.x; t[tr][tc + 1] = v.y; t[tr][tc + 2] = v.z; t[tr][tc + 3] = v.w;
        __syncthreads();
        ushort4v o = { f2bf(t[tc + 0][tr]), f2bf(t[tc + 1][tr]),
                       f2bf(t[tc + 2][tr]), f2bf(t[tc + 3][tr]) };
        *(ushort4v*)(outp + (size_t)(n0 + tr) * K + k0 + tc) = o;
    } else if (bx < INIT_B) {
        // ---- embed gather: 2 rows per block ----
        const int r = (bx - GATH_B) * 2 + (tid >> 7);
        const int v = idx[r];
        const int c = (tid & 127) * 4;
        float4 f = *(const float4*)(emb + (size_t)v * E + c);
        ushort4v o = { f2bf(f.x), f2bf(f.y), f2bf(f.z), f2bf(f.w) };
        *(ushort4v*)(X + (size_t)r * E + c) = o;
    } else if (bx < ZERO_B) {
        // ---- init_prep: 2 rows per block ----
        const int r = (bx - INIT_B) * 2 + (tid >> 7);
        const int c = (tid & 127) * 4;
        float4 f = *(const float4*)(init + (size_t)r * H + c);
        ushort4v o = { f2bf(f.x), f2bf(f.y), f2bf(f.z), f2bf(f.w) };
        *(ushort4v*)(h0 + (size_t)r * H + c) = o;
        *(ushort4v*)(S + ((size_t)r * T_) * H + c) = o;
    } else {
        // ---- out seed + sync zero ----
        const int i = (bx - ZERO_B) * 256 + tid;
        if (i < 256) out[i] = (float)T_ * b2[0];
        else if (i < 256 + 256 + 4096) sync_ints[i - 256] = 0;
    }
}

// ---------------------------------------------------------------------------
// K2: persistent fused LSTM recurrence + fused x@Wx. (FROZEN R8/R9 form)
// 256 blocks x 512 threads (8 waves) = 1 block/CU, 2 waves/SIMD (R8-proven).
// XCD discovery -> 16-block teams. Per-wave tile: 4 gates x 4 cols; epilogue
// via 4x4 quad-transpose (3 shfl_xor, R8-verified). Sync: per-block slot
// STORES at 64B stride; poll = lane-indexed AGENT load + __all.
// ---------------------------------------------------------------------------
__global__ __launch_bounds__(512, 2) void lstm_fused_main(
    const ushort* __restrict__ WhT, const ushort* __restrict__ WxT,
    const ushort* __restrict__ Xbf, const float* __restrict__ bg,
    const float*  __restrict__ init_state, const ushort* __restrict__ h0,
    ushort* __restrict__ pp0, ushort* __restrict__ pp1,
    ushort* __restrict__ S, int* __restrict__ xcd_tbl, int* __restrict__ cnts)
{
    __shared__ __align__(16) ushort hsh[16 * PITCH_US];
    __shared__ __align__(16) ushort xsh[2][16 * PITCH_US];
    __shared__ int exl[256];

    const int tid  = threadIdx.x;
    const int wave = tid >> 6, lane = tid & 63;
    const int quad = lane >> 4, l16 = lane & 15;

    // ---- one-time team discovery (bounded) ----
    int xcd;
    asm volatile("s_getreg_b32 %0, hwreg(HW_REG_XCC_ID)" : "=s"(xcd));
    if (tid == 0)
        __hip_atomic_store(&xcd_tbl[blockIdx.x], (xcd & 7) + 1,
                           __ATOMIC_RELAXED, __HIP_MEMORY_SCOPE_AGENT);
    if (wave == 0) {
        for (int it = 0; it < SPIN_CAP; ++it) {
            int miss = 0;
#pragma unroll
            for (int j = 0; j < 4; ++j) {
                int i = lane + j * 64;
                int v = __hip_atomic_load(&xcd_tbl[i], __ATOMIC_RELAXED,
                                          __HIP_MEMORY_SCOPE_AGENT);
                exl[i] = (v == 0) ? 0 : (v - 1);
                if (v == 0) miss = 1;
            }
            if (!__any(miss)) break;
            __builtin_amdgcn_s_sleep(4);
        }
    }
    BAR_LGKM();

    // deterministic assignment (identical scan in every thread)
    int g = 0, m = 0, loc = 0;
    {
        int cntx[8] = {0,0,0,0,0,0,0,0};
        for (int i = 0; i < 256; ++i) cntx[exl[i] & 7]++;
        int take[8], base[8], tA = 0;
        for (int x = 0; x < 8; ++x) {
            int tk = cntx[x] >> 4;
            if (tA + tk > 16) tk = 16 - tA;
            take[x] = tk; base[x] = tA; tA += tk;
        }
        int rc[8] = {0,0,0,0,0,0,0,0}, lc = 0;
        for (int i = 0; i < 256; ++i) {
            int x = exl[i] & 7, r = rc[x]++;
            if ((r >> 4) < take[x]) {
                if (i == (int)blockIdx.x) { g = base[x] + (r >> 4); m = r & 15; loc = 1; }
            } else {
                if (i == (int)blockIdx.x) { g = tA + (lc >> 4); m = lc & 15; loc = 0; }
                lc++;
            }
        }
    }

    const int n0    = g * 16;
    const int jw    = m * 32 + wave * 4;   // wave's 4 hidden-cols
    const int koff  = quad * 8;
    const int myrow = n0 + l16;
    const int hcol  = jw + quad;           // this thread's output hidden-col

    // A-frag preloads: one tile = 4 gates x 4 cols.
    short8 af[16], ax[16];
    {
        const size_t rowoff =
            (size_t)((l16 >> 2) * 512 + jw + (l16 & 3)) * 512 + koff;
        const ushort* bh = WhT + rowoff;
        const ushort* bx = WxT + rowoff;
#pragma unroll
        for (int kk = 0; kk < 16; ++kk) {
            af[kk] = *(const short8*)(bh + kk * 32);
            ax[kk] = *(const short8*)(bx + kk * 32);
        }
    }

    // bias: gate = quad, cols jw..jw+3 (added pre-transpose)
    float bgq[4];
#pragma unroll
    for (int r = 0; r < 4; ++r) bgq[r] = bg[quad * 512 + jw + r];

    // c-state: one (row, col) per thread
    float c1 = init_state[(size_t)myrow * H + hcol];

    // staging coords: 2 granules of 16B per thread (512 thr x 2 = 16x64)
    int gr[2], gc[2], lo[2];
#pragma unroll
    for (int j = 0; j < 2; ++j) {
        int lin = tid + j * 512;
        gr[j] = lin >> 6; gc[j] = lin & 63;
        lo[j] = gr[j] * PITCH_US + gc[j] * 8;
    }

    // stage x(0) into xsh[0]
#pragma unroll
    for (int j = 0; j < 2; ++j) {
        i32x4 v = *(const i32x4*)(Xbf + ((size_t)(n0 + gr[j]) * T_) * H + gc[j] * 8);
        *(i32x4*)&xsh[0][lo[j]] = v;
    }
    BAR_LGKM();

    // signal slots: 16 per team, 64B (16-int) stride (R9)
    int* slots = cnts + g * 256;              // 1KB apart per team
    int* myslot = slots + m * 16;
    const int* pollp = slots + (lane & 15) * 16;  // lane l -> slot l&15
    const int frag_base = l16 * PITCH_US + quad * 8;   // + kk*32

    for (int t = 0; t < T_ - 1; ++t) {
        // a) issue x(t+1) prefetch (plain cached loads)
        i32x4 xv0, xv1;
        const int have_x = (t + 1 < T_ - 1);
        if (have_x) {
            xv0 = *(const i32x4*)(Xbf + ((size_t)(n0 + gr[0]) * T_ + t + 1) * H + gc[0] * 8);
            xv1 = *(const i32x4*)(Xbf + ((size_t)(n0 + gr[1]) * T_ + t + 1) * H + gc[1] * 8);
        }

        // b) x-part MFMA (independent of h -> overlaps the wait)
        f32x4 axx = {};
        {
            const ushort* xb = xsh[t & 1];
#pragma unroll
            for (int kk = 0; kk < 16; ++kk) {
                short8 b = *(const short8*)&xb[frag_base + kk * 32];
                axx = __builtin_amdgcn_mfma_f32_16x16x32_bf16(ax[kk], b, axx, 0, 0, 0);
            }
        }

        // c) wait for teammates' h(t): lane-indexed slot poll, __all
        if (t > 0) {
            for (int it = 0; it < POLL_CAP; ++it) {
                int v = __hip_atomic_load(pollp, __ATOMIC_RELAXED,
                                          __HIP_MEMORY_SCOPE_AGENT);
                if (__all(v >= t)) break;
                __builtin_amdgcn_s_sleep(1);
            }
        }

        // d) stage h(t) into LDS (16B loads; local L2 for loc teams)
        {
            const ushort* hin = (t == 0) ? h0 : ((t & 1) ? pp0 : pp1);
            const ushort* p0 = hin + (size_t)(n0 + gr[0]) * H + gc[0] * 8;
            const ushort* p1 = hin + (size_t)(n0 + gr[1]) * H + gc[1] * 8;
            i32x4 v0, v1;
            if (loc) { LOAD2_SC0(v0, v1, p0, p1); }
            else     { LOAD2_SC01(v0, v1, p0, p1); }
            *(i32x4*)&hsh[lo[0]] = v0;
            *(i32x4*)&hsh[lo[1]] = v1;
        }
        BAR_LGKM();

        // e) h-part MFMA
        f32x4 ah = {};
#pragma unroll
        for (int kk = 0; kk < 16; ++kk) {
            short8 b = *(const short8*)&hsh[frag_base + kk * 32];
            ah = __builtin_amdgcn_mfma_f32_16x16x32_bf16(af[kk], b, ah, 0, 0, 0);
        }

        // f) write x(t+1) into the other xsh buffer
        if (have_x) {
            ushort* xb = xsh[(t + 1) & 1];
            *(i32x4*)&xb[lo[0]] = xv0;
            *(i32x4*)&xb[lo[1]] = xv1;
        }

        // g) epilogue. 4x4 quad-transpose (R8-verified mapping).
        float g4[4];
#pragma unroll
        for (int r = 0; r < 4; ++r) g4[r] = ah[r] + axx[r] + bgq[r];
        float s1 = (quad & 1) ? ((quad & 2) ? g4[2] : g4[0])
                              : ((quad & 2) ? g4[3] : g4[1]);
        float s2 = (quad & 2) ? ((quad & 1) ? g4[1] : g4[0])
                              : ((quad & 1) ? g4[3] : g4[2]);
        float s3 = (quad & 2) ? ((quad & 1) ? g4[0] : g4[1])
                              : ((quad & 1) ? g4[2] : g4[3]);
        float r0 = (quad & 1) ? ((quad & 2) ? g4[3] : g4[1])
                              : ((quad & 2) ? g4[2] : g4[0]);
        float r1 = __shfl_xor(s1, 16, 64);
        float r2 = __shfl_xor(s2, 32, 64);
        float r3 = __shfl_xor(s3, 48, 64);
        float iv = (quad == 0) ? r0 : (quad == 1) ? r1 : (quad == 2) ? r2 : r3;
        float fv = (quad == 0) ? r1 : (quad == 1) ? r0 : (quad == 2) ? r3 : r2;
        float gv = (quad == 0) ? r2 : (quad == 1) ? r3 : (quad == 2) ? r0 : r1;
        float ov = (quad == 0) ? r3 : (quad == 1) ? r2 : (quad == 2) ? r1 : r0;
        iv = fast_sig(iv);
        fv = fast_sig(fv);
        gv = fast_tanh(gv);
        ov = fast_sig(ov);
        float cn = fv * c1 + iv * gv;
        c1 = cn;
        ushort ho = f2bf(ov * fast_tanh(cn));

        // h) h store (exchange buffer): 2B per lane, every lane distinct
        ushort* hout = (t & 1) ? pp1 : pp0;
        {
            ushort* hp2 = hout + (size_t)myrow * H + hcol;
            if (loc) *hp2 = ho;
            else asm volatile("global_store_short %0, %1, off sc0 sc1"
                              :: "v"(hp2), "v"((int)ho) : "memory");
        }

        // i) drain h store, block barrier, then per-block slot STORE
        BAR_ALL();
        if (tid == 0)
            __hip_atomic_store(myslot, t + 1, __ATOMIC_RELAXED,
                               __HIP_MEMORY_SCOPE_AGENT);

        // j) S store AFTER the signal — drained by a later vmcnt(0)
        S[((size_t)myrow * T_ + (t + 1)) * H + hcol] = ho;
    }
}

// ---------------------------------------------------------------------------
// K3: phase C fused with score head AND final reduce (R11).
// R9-proven grid (4,128): n-split across blockIdx.x keeps all CUs busy
// (R10 errata: n-folding halved parallelism and regressed). Final values
// atomicAdd straight into out[row/64] — scores buffer and reduce kernel
// eliminated; out pre-seeded with T*b2 by prep_all.
// ---------------------------------------------------------------------------
__global__ __launch_bounds__(256) void gemm_score(
    const ushort* __restrict__ Sm, const ushort* __restrict__ Xbf,
    const ushort* __restrict__ W1T,   // [256][1024]
    const float* __restrict__ b1, const float* __restrict__ W2,
    float* __restrict__ out)
{
    const int tid  = threadIdx.x;
    const int wave = tid >> 6, lane = tid & 63;
    const int quad = lane >> 4, l16 = lane & 15;
    const int m0 = blockIdx.y * 128 + wave * 32;
    const int n0 = blockIdx.x * 64;
    const int koff = quad * 8;

    f32x4 acc[2][4] = {};

    for (int src = 0; src < 2; ++src) {
        const ushort* A  = src ? Xbf : Sm;
        const ushort* Bm = W1T + src * 512;
        const ushort* a0p = A + (size_t)(m0 + l16) * H + koff;
        const ushort* a1p = A + (size_t)(m0 + 16 + l16) * H + koff;
        const ushort* bp  = Bm + (size_t)(n0 + l16) * 1024 + koff;
        for (int kk = 0; kk < H; kk += 32) {
            short8 a0 = *(const short8*)(a0p + kk);
            short8 a1 = *(const short8*)(a1p + kk);
#pragma unroll
            for (int nf = 0; nf < 4; ++nf) {
                short8 b = *(const short8*)(bp + (size_t)nf * 16 * 1024 + kk);
                acc[0][nf] = __builtin_amdgcn_mfma_f32_16x16x32_bf16(a0, b, acc[0][nf], 0, 0, 0);
                acc[1][nf] = __builtin_amdgcn_mfma_f32_16x16x32_bf16(a1, b, acc[1][nf], 0, 0, 0);
            }
        }
    }

    float w2v[4], b1v[4];
#pragma unroll
    for (int nf = 0; nf < 4; ++nf) {
        const int col = n0 + nf * 16 + l16;
        w2v[nf] = W2[col];
        b1v[nf] = b1[col];
    }

#pragma unroll
    for (int mf = 0; mf < 2; ++mf) {
#pragma unroll
        for (int r = 0; r < 4; ++r) {
            float p = 0.f;
#pragma unroll
            for (int nf = 0; nf < 4; ++nf)
                p += fmaxf(acc[mf][nf][r] + b1v[nf], 0.f) * w2v[nf];
            p += __shfl_xor(p, 1, 64);
            p += __shfl_xor(p, 2, 64);
            p += __shfl_xor(p, 4, 64);
            p += __shfl_xor(p, 8, 64);
            if (l16 == 0) {
                const int row = m0 + mf * 16 + quad * 4 + r;
                atomicAdd(&out[row >> 6], p);   // sum over t is linear
            }
        }
    }
}

// ---------------------------------------------------------------------------
extern "C" void kernel_launch(void* const* d_in, const int* in_sizes, int n_in,
                              void* d_out, int out_size, void* d_ws, size_t ws_size,
                              hipStream_t stream)
{
    const float* init_state = (const float*)d_in[0];
    const float* choice_emb = (const float*)d_in[1];
    const int*   arg_seq    = (const int*)  d_in[2];
    const float* Wx         = (const float*)d_in[3];
    const float* Wh         = (const float*)d_in[4];
    const float* bg         = (const float*)d_in[5];
    const float* W1         = (const float*)d_in[6];
    const float* b1         = (const float*)d_in[7];
    const float* W2         = (const float*)d_in[8];
    const float* b2         = (const float*)d_in[9];
    float* out = (float*)d_out;

    // workspace layout
    ushort* WxT = (ushort*)d_ws;                 // [2048,512] bf16
    ushort* WhT = WxT + 1048576;                 // [2048,512] bf16
    ushort* W1T = WhT + 1048576;                 // [256,1024] bf16
    ushort* Xbf = W1T + 262144;                  // [BT,512]  bf16
    ushort* S   = Xbf + 8388608;                 // [B,T,H]   bf16
    ushort* h0  = S   + 8388608;                 // [B,H]
    ushort* pp0 = h0  + 131072;                  // [B,H]
    ushort* pp1 = pp0 + 131072;                  // [B,H]
    float*  scores  = (float*)(pp1 + 131072);    // [BT] (unused, kept for layout)
    int*    xcd_tbl = (int*)(scores + BT);       // [256]
    int*    cnts    = xcd_tbl + 256;             // [16 teams * 256] slot arrays

    // ONE prep launch: weights || gather || init || out-seed+sync-zero
    prep_all<<<PALL_N, 256, 0, stream>>>(
        Wx, Wh, W1, WxT, WhT, W1T,
        choice_emb, arg_seq, Xbf,
        init_state, h0, S,
        out, b2, xcd_tbl);

    // Phase A+B fused: persistent recurrence with in-kernel x@Wx
    lstm_fused_main<<<256, 512, 0, stream>>>(
        WhT, WxT, Xbf, bg, init_state, h0, pp0, pp1, S, xcd_tbl, cnts);

    // Phase C+D+reduce fused: atomics straight into out
    gemm_score<<<dim3(C1 / 64, BT / 128), 256, 0, stream>>>(
        S, Xbf, W1T, b1, W2, out);
}

// Round 12
// 375.255 us; speedup vs baseline: 1.2565x; 1.2565x over previous
//
#include <hip/hip_runtime.h>
#include <hip/hip_bf16.h>
#include <math.h>

// Problem constants
#define H   512
#define E   512
#define B_  256
#define T_  64
#define G4  2048   // 4*H
#define C1  256    // MLP hidden
#define BT  16384  // B*T

#define SPIN_CAP (1 << 22)   // discovery spin bound (dispatch latency)
#define POLL_CAP (1 << 18)   // per-step poll bound: failure -> slow-but-correct

typedef __attribute__((ext_vector_type(8))) short  short8;   // 8 bf16 (4 VGPRs)
typedef __attribute__((ext_vector_type(4))) float  f32x4;    // MFMA acc
typedef __attribute__((ext_vector_type(4))) int    i32x4;    // 16B granule
typedef __attribute__((ext_vector_type(4))) unsigned short ushort4v;
typedef unsigned short ushort;
typedef unsigned long long u64;

// LDS tile: row-major [row][kc granule], pitch 65 granules (odd) = 520 ushorts.
#define PITCH_US 520

#define BAR_LGKM() asm volatile("s_waitcnt lgkmcnt(0)\n\ts_barrier" ::: "memory")
#define BAR_ALL()  asm volatile("s_waitcnt vmcnt(0) lgkmcnt(0)\n\ts_barrier" ::: "memory")

// ---------------------------------------------------------------------------
// Design ledger (R0-R11, measured on MI355X):
//   - Cross-CU flags MUST go through the MALL (AGENT both sides). Local-L2
//     signaling impossible (R2/R3/R4). Streamed data lines work plain->sc0.
//   - Sync chain fully bracketed: poll contention (R5), RMW convoy at 16
//     adds/line (R9) null; per-wave dataflow (R7) negative. Block-lockstep
//     + LDS staging + 2 waves/SIMD (R8, 247us) is the optimum; lstm FROZEN.
//   - gemm n-fold (R10) regressed: parallelism-bound, keep grid (4,128).
//   - R11 errata: fused reduce did 65536 atomicAdds on 16 lines (4096/line)
//     -> ~50-80us MALL RMW convoy (matches +90us). Same-line atomics ARE
//     the convoy mechanism at high multiplicity; R9's null was 16/line.
//   - R12 (this): reduce algebra folded per-wave — each wave's 32 rows lie
//     in one batch; psum over (mf,r), full 64-lane shfl reduce, ONE
//     atomicAdd/wave (2048 total, 128/line = proven-cheap level).
// ---------------------------------------------------------------------------

__device__ __forceinline__ ushort f2bf(float x) {
    unsigned u = __builtin_bit_cast(unsigned, x);
    unsigned r = (u + 0x7FFFu + ((u >> 16) & 1u)) >> 16;
    return (ushort)r;
}
__device__ __forceinline__ float fast_sig(float x) {
    return __builtin_amdgcn_rcpf(1.f + __expf(-x));
}
__device__ __forceinline__ float fast_tanh(float x) {
    return 1.f - 2.f * __builtin_amdgcn_rcpf(1.f + __expf(2.f * x));
}

// 2x 16B loads, batched, drained. sc0: L1-bypass, local XCD L2 (R8-proven).
#define LOAD2_SC0(v0,v1,p0,p1) \
  asm volatile("global_load_dwordx4 %0, %2, off sc0\n\t" \
               "global_load_dwordx4 %1, %3, off sc0\n\t" \
               "s_waitcnt vmcnt(0)" \
               : "=&v"(v0), "=&v"(v1) : "v"(p0), "v"(p1) : "memory")
#define LOAD2_SC01(v0,v1,p0,p1) \
  asm volatile("global_load_dwordx4 %0, %2, off sc0 sc1\n\t" \
               "global_load_dwordx4 %1, %3, off sc0 sc1\n\t" \
               "s_waitcnt vmcnt(0)" \
               : "=&v"(v0), "=&v"(v1) : "v"(p0), "v"(p1) : "memory")

// ---------------------------------------------------------------------------
// P*: fused prep — ONE launch, grid-partitioned, all sections independent:
//   [0, 2304)          weight transpose+cast fp32 [K][N] -> bf16 [N][K]
//   [2304, 10496)      embed gather: 2 rows/block (128 thr each half)
//   [10496, 10624)     init_prep: 2 rows/block
//   [10624, 10642)     out[b] = T*b2 seed + zero xcd_tbl/cnts
// ---------------------------------------------------------------------------
#define PREP_N  2304
#define GATH_B  (PREP_N)
#define GATH_N  (BT / 2)
#define INIT_B  (GATH_B + GATH_N)
#define INIT_N  (B_ / 2)
#define ZERO_B  (INIT_B + INIT_N)
#define ZERO_N  18
#define PALL_N  (ZERO_B + ZERO_N)

__global__ __launch_bounds__(256) void prep_all(
    const float* __restrict__ Wx, const float* __restrict__ Wh,
    const float* __restrict__ W1,
    ushort* __restrict__ WxT, ushort* __restrict__ WhT, ushort* __restrict__ W1T,
    const float* __restrict__ emb, const int* __restrict__ idx,
    ushort* __restrict__ X,
    const float* __restrict__ init, ushort* __restrict__ h0,
    ushort* __restrict__ S,
    float* __restrict__ out, const float* __restrict__ b2,
    int* __restrict__ sync_ints)
{
    const int tid = threadIdx.x;
    int bx = blockIdx.x;

    if (bx < PREP_N) {
        // ---- weight transpose + cast ----
        __shared__ float t[32][33];
        const float* in; ushort* outp; int K, N, k0, n0;
        if (bx < 1024)       { in = Wx; outp = WxT; K = 512;  N = 2048; k0 = (bx >> 6) * 32; n0 = (bx & 63) * 32; }
        else if (bx < 2048)  { bx -= 1024; in = Wh; outp = WhT; K = 512;  N = 2048; k0 = (bx >> 6) * 32; n0 = (bx & 63) * 32; }
        else                 { bx -= 2048; in = W1; outp = W1T; K = 1024; N = 256;  k0 = (bx >> 3) * 32; n0 = (bx & 7) * 32; }
        const int tr = tid >> 3;
        const int tc = (tid & 7) * 4;
        float4 v = *(const float4*)(in + (size_t)(k0 + tr) * N + n0 + tc);
        t[tr][tc + 0] = v.x; t[tr][tc + 1] = v.y; t[tr][tc + 2] = v.z; t[tr][tc + 3] = v.w;
        __syncthreads();
        ushort4v o = { f2bf(t[tc + 0][tr]), f2bf(t[tc + 1][tr]),
                       f2bf(t[tc + 2][tr]), f2bf(t[tc + 3][tr]) };
        *(ushort4v*)(outp + (size_t)(n0 + tr) * K + k0 + tc) = o;
    } else if (bx < INIT_B) {
        // ---- embed gather: 2 rows per block ----
        const int r = (bx - GATH_B) * 2 + (tid >> 7);
        const int v = idx[r];
        const int c = (tid & 127) * 4;
        float4 f = *(const float4*)(emb + (size_t)v * E + c);
        ushort4v o = { f2bf(f.x), f2bf(f.y), f2bf(f.z), f2bf(f.w) };
        *(ushort4v*)(X + (size_t)r * E + c) = o;
    } else if (bx < ZERO_B) {
        // ---- init_prep: 2 rows per block ----
        const int r = (bx - INIT_B) * 2 + (tid >> 7);
        const int c = (tid & 127) * 4;
        float4 f = *(const float4*)(init + (size_t)r * H + c);
        ushort4v o = { f2bf(f.x), f2bf(f.y), f2bf(f.z), f2bf(f.w) };
        *(ushort4v*)(h0 + (size_t)r * H + c) = o;
        *(ushort4v*)(S + ((size_t)r * T_) * H + c) = o;
    } else {
        // ---- out seed + sync zero ----
        const int i = (bx - ZERO_B) * 256 + tid;
        if (i < 256) out[i] = (float)T_ * b2[0];
        else if (i < 256 + 256 + 4096) sync_ints[i - 256] = 0;
    }
}

// ---------------------------------------------------------------------------
// K2: persistent fused LSTM recurrence + fused x@Wx. (FROZEN R8/R9 form)
// 256 blocks x 512 threads (8 waves) = 1 block/CU, 2 waves/SIMD (R8-proven).
// XCD discovery -> 16-block teams. Per-wave tile: 4 gates x 4 cols; epilogue
// via 4x4 quad-transpose (3 shfl_xor, R8-verified). Sync: per-block slot
// STORES at 64B stride; poll = lane-indexed AGENT load + __all.
// ---------------------------------------------------------------------------
__global__ __launch_bounds__(512, 2) void lstm_fused_main(
    const ushort* __restrict__ WhT, const ushort* __restrict__ WxT,
    const ushort* __restrict__ Xbf, const float* __restrict__ bg,
    const float*  __restrict__ init_state, const ushort* __restrict__ h0,
    ushort* __restrict__ pp0, ushort* __restrict__ pp1,
    ushort* __restrict__ S, int* __restrict__ xcd_tbl, int* __restrict__ cnts)
{
    __shared__ __align__(16) ushort hsh[16 * PITCH_US];
    __shared__ __align__(16) ushort xsh[2][16 * PITCH_US];
    __shared__ int exl[256];

    const int tid  = threadIdx.x;
    const int wave = tid >> 6, lane = tid & 63;
    const int quad = lane >> 4, l16 = lane & 15;

    // ---- one-time team discovery (bounded) ----
    int xcd;
    asm volatile("s_getreg_b32 %0, hwreg(HW_REG_XCC_ID)" : "=s"(xcd));
    if (tid == 0)
        __hip_atomic_store(&xcd_tbl[blockIdx.x], (xcd & 7) + 1,
                           __ATOMIC_RELAXED, __HIP_MEMORY_SCOPE_AGENT);
    if (wave == 0) {
        for (int it = 0; it < SPIN_CAP; ++it) {
            int miss = 0;
#pragma unroll
            for (int j = 0; j < 4; ++j) {
                int i = lane + j * 64;
                int v = __hip_atomic_load(&xcd_tbl[i], __ATOMIC_RELAXED,
                                          __HIP_MEMORY_SCOPE_AGENT);
                exl[i] = (v == 0) ? 0 : (v - 1);
                if (v == 0) miss = 1;
            }
            if (!__any(miss)) break;
            __builtin_amdgcn_s_sleep(4);
        }
    }
    BAR_LGKM();

    // deterministic assignment (identical scan in every thread)
    int g = 0, m = 0, loc = 0;
    {
        int cntx[8] = {0,0,0,0,0,0,0,0};
        for (int i = 0; i < 256; ++i) cntx[exl[i] & 7]++;
        int take[8], base[8], tA = 0;
        for (int x = 0; x < 8; ++x) {
            int tk = cntx[x] >> 4;
            if (tA + tk > 16) tk = 16 - tA;
            take[x] = tk; base[x] = tA; tA += tk;
        }
        int rc[8] = {0,0,0,0,0,0,0,0}, lc = 0;
        for (int i = 0; i < 256; ++i) {
            int x = exl[i] & 7, r = rc[x]++;
            if ((r >> 4) < take[x]) {
                if (i == (int)blockIdx.x) { g = base[x] + (r >> 4); m = r & 15; loc = 1; }
            } else {
                if (i == (int)blockIdx.x) { g = tA + (lc >> 4); m = lc & 15; loc = 0; }
                lc++;
            }
        }
    }

    const int n0    = g * 16;
    const int jw    = m * 32 + wave * 4;   // wave's 4 hidden-cols
    const int koff  = quad * 8;
    const int myrow = n0 + l16;
    const int hcol  = jw + quad;           // this thread's output hidden-col

    // A-frag preloads: one tile = 4 gates x 4 cols.
    short8 af[16], ax[16];
    {
        const size_t rowoff =
            (size_t)((l16 >> 2) * 512 + jw + (l16 & 3)) * 512 + koff;
        const ushort* bh = WhT + rowoff;
        const ushort* bx = WxT + rowoff;
#pragma unroll
        for (int kk = 0; kk < 16; ++kk) {
            af[kk] = *(const short8*)(bh + kk * 32);
            ax[kk] = *(const short8*)(bx + kk * 32);
        }
    }

    // bias: gate = quad, cols jw..jw+3 (added pre-transpose)
    float bgq[4];
#pragma unroll
    for (int r = 0; r < 4; ++r) bgq[r] = bg[quad * 512 + jw + r];

    // c-state: one (row, col) per thread
    float c1 = init_state[(size_t)myrow * H + hcol];

    // staging coords: 2 granules of 16B per thread (512 thr x 2 = 16x64)
    int gr[2], gc[2], lo[2];
#pragma unroll
    for (int j = 0; j < 2; ++j) {
        int lin = tid + j * 512;
        gr[j] = lin >> 6; gc[j] = lin & 63;
        lo[j] = gr[j] * PITCH_US + gc[j] * 8;
    }

    // stage x(0) into xsh[0]
#pragma unroll
    for (int j = 0; j < 2; ++j) {
        i32x4 v = *(const i32x4*)(Xbf + ((size_t)(n0 + gr[j]) * T_) * H + gc[j] * 8);
        *(i32x4*)&xsh[0][lo[j]] = v;
    }
    BAR_LGKM();

    // signal slots: 16 per team, 64B (16-int) stride (R9)
    int* slots = cnts + g * 256;              // 1KB apart per team
    int* myslot = slots + m * 16;
    const int* pollp = slots + (lane & 15) * 16;  // lane l -> slot l&15
    const int frag_base = l16 * PITCH_US + quad * 8;   // + kk*32

    for (int t = 0; t < T_ - 1; ++t) {
        // a) issue x(t+1) prefetch (plain cached loads)
        i32x4 xv0, xv1;
        const int have_x = (t + 1 < T_ - 1);
        if (have_x) {
            xv0 = *(const i32x4*)(Xbf + ((size_t)(n0 + gr[0]) * T_ + t + 1) * H + gc[0] * 8);
            xv1 = *(const i32x4*)(Xbf + ((size_t)(n0 + gr[1]) * T_ + t + 1) * H + gc[1] * 8);
        }

        // b) x-part MFMA (independent of h -> overlaps the wait)
        f32x4 axx = {};
        {
            const ushort* xb = xsh[t & 1];
#pragma unroll
            for (int kk = 0; kk < 16; ++kk) {
                short8 b = *(const short8*)&xb[frag_base + kk * 32];
                axx = __builtin_amdgcn_mfma_f32_16x16x32_bf16(ax[kk], b, axx, 0, 0, 0);
            }
        }

        // c) wait for teammates' h(t): lane-indexed slot poll, __all
        if (t > 0) {
            for (int it = 0; it < POLL_CAP; ++it) {
                int v = __hip_atomic_load(pollp, __ATOMIC_RELAXED,
                                          __HIP_MEMORY_SCOPE_AGENT);
                if (__all(v >= t)) break;
                __builtin_amdgcn_s_sleep(1);
            }
        }

        // d) stage h(t) into LDS (16B loads; local L2 for loc teams)
        {
            const ushort* hin = (t == 0) ? h0 : ((t & 1) ? pp0 : pp1);
            const ushort* p0 = hin + (size_t)(n0 + gr[0]) * H + gc[0] * 8;
            const ushort* p1 = hin + (size_t)(n0 + gr[1]) * H + gc[1] * 8;
            i32x4 v0, v1;
            if (loc) { LOAD2_SC0(v0, v1, p0, p1); }
            else     { LOAD2_SC01(v0, v1, p0, p1); }
            *(i32x4*)&hsh[lo[0]] = v0;
            *(i32x4*)&hsh[lo[1]] = v1;
        }
        BAR_LGKM();

        // e) h-part MFMA
        f32x4 ah = {};
#pragma unroll
        for (int kk = 0; kk < 16; ++kk) {
            short8 b = *(const short8*)&hsh[frag_base + kk * 32];
            ah = __builtin_amdgcn_mfma_f32_16x16x32_bf16(af[kk], b, ah, 0, 0, 0);
        }

        // f) write x(t+1) into the other xsh buffer
        if (have_x) {
            ushort* xb = xsh[(t + 1) & 1];
            *(i32x4*)&xb[lo[0]] = xv0;
            *(i32x4*)&xb[lo[1]] = xv1;
        }

        // g) epilogue. 4x4 quad-transpose (R8-verified mapping).
        float g4[4];
#pragma unroll
        for (int r = 0; r < 4; ++r) g4[r] = ah[r] + axx[r] + bgq[r];
        float s1 = (quad & 1) ? ((quad & 2) ? g4[2] : g4[0])
                              : ((quad & 2) ? g4[3] : g4[1]);
        float s2 = (quad & 2) ? ((quad & 1) ? g4[1] : g4[0])
                              : ((quad & 1) ? g4[3] : g4[2]);
        float s3 = (quad & 2) ? ((quad & 1) ? g4[0] : g4[1])
                              : ((quad & 1) ? g4[2] : g4[3]);
        float r0 = (quad & 1) ? ((quad & 2) ? g4[3] : g4[1])
                              : ((quad & 2) ? g4[2] : g4[0]);
        float r1 = __shfl_xor(s1, 16, 64);
        float r2 = __shfl_xor(s2, 32, 64);
        float r3 = __shfl_xor(s3, 48, 64);
        float iv = (quad == 0) ? r0 : (quad == 1) ? r1 : (quad == 2) ? r2 : r3;
        float fv = (quad == 0) ? r1 : (quad == 1) ? r0 : (quad == 2) ? r3 : r2;
        float gv = (quad == 0) ? r2 : (quad == 1) ? r3 : (quad == 2) ? r0 : r1;
        float ov = (quad == 0) ? r3 : (quad == 1) ? r2 : (quad == 2) ? r1 : r0;
        iv = fast_sig(iv);
        fv = fast_sig(fv);
        gv = fast_tanh(gv);
        ov = fast_sig(ov);
        float cn = fv * c1 + iv * gv;
        c1 = cn;
        ushort ho = f2bf(ov * fast_tanh(cn));

        // h) h store (exchange buffer): 2B per lane, every lane distinct
        ushort* hout = (t & 1) ? pp1 : pp0;
        {
            ushort* hp2 = hout + (size_t)myrow * H + hcol;
            if (loc) *hp2 = ho;
            else asm volatile("global_store_short %0, %1, off sc0 sc1"
                              :: "v"(hp2), "v"((int)ho) : "memory");
        }

        // i) drain h store, block barrier, then per-block slot STORE
        BAR_ALL();
        if (tid == 0)
            __hip_atomic_store(myslot, t + 1, __ATOMIC_RELAXED,
                               __HIP_MEMORY_SCOPE_AGENT);

        // j) S store AFTER the signal — drained by a later vmcnt(0)
        S[((size_t)myrow * T_ + (t + 1)) * H + hcol] = ho;
    }
}

// ---------------------------------------------------------------------------
// K3: phase C fused with score head AND final reduce (R12 form).
// R9-proven grid (4,128). Each wave's 32 rows (m0..m0+31) lie entirely in
// batch by*2 + (wave>>1), and out[b] = sum over rows AND cols (all linear
// after the per-(row,col) relu). So: per-thread psum over (mf,r), full
// 64-lane shfl reduce (sums cols via l16 and rows via quad lanes), ONE
// atomicAdd per wave -> 2048 atomics total (128/line, R9-proven-cheap;
// R11 errata: 65536 atomics = 4096/line convoyed ~50-80us).
// out pre-seeded with T*b2 by prep_all.
// ---------------------------------------------------------------------------
__global__ __launch_bounds__(256) void gemm_score(
    const ushort* __restrict__ Sm, const ushort* __restrict__ Xbf,
    const ushort* __restrict__ W1T,   // [256][1024]
    const float* __restrict__ b1, const float* __restrict__ W2,
    float* __restrict__ out)
{
    const int tid  = threadIdx.x;
    const int wave = tid >> 6, lane = tid & 63;
    const int quad = lane >> 4, l16 = lane & 15;
    const int m0 = blockIdx.y * 128 + wave * 32;
    const int n0 = blockIdx.x * 64;
    const int koff = quad * 8;

    f32x4 acc[2][4] = {};

    for (int src = 0; src < 2; ++src) {
        const ushort* A  = src ? Xbf : Sm;
        const ushort* Bm = W1T + src * 512;
        const ushort* a0p = A + (size_t)(m0 + l16) * H + koff;
        const ushort* a1p = A + (size_t)(m0 + 16 + l16) * H + koff;
        const ushort* bp  = Bm + (size_t)(n0 + l16) * 1024 + koff;
        for (int kk = 0; kk < H; kk += 32) {
            short8 a0 = *(const short8*)(a0p + kk);
            short8 a1 = *(const short8*)(a1p + kk);
#pragma unroll
            for (int nf = 0; nf < 4; ++nf) {
                short8 b = *(const short8*)(bp + (size_t)nf * 16 * 1024 + kk);
                acc[0][nf] = __builtin_amdgcn_mfma_f32_16x16x32_bf16(a0, b, acc[0][nf], 0, 0, 0);
                acc[1][nf] = __builtin_amdgcn_mfma_f32_16x16x32_bf16(a1, b, acc[1][nf], 0, 0, 0);
            }
        }
    }

    float w2v[4], b1v[4];
#pragma unroll
    for (int nf = 0; nf < 4; ++nf) {
        const int col = n0 + nf * 16 + l16;
        w2v[nf] = W2[col];
        b1v[nf] = b1[col];
    }

    // per-thread partial: relu per (row,col), dot W2, summed over the
    // thread's 8 rows (mf,r) — all rows belong to this wave's batch.
    float psum = 0.f;
#pragma unroll
    for (int mf = 0; mf < 2; ++mf)
#pragma unroll
    for (int r = 0; r < 4; ++r) {
#pragma unroll
        for (int nf = 0; nf < 4; ++nf)
            psum += fmaxf(acc[mf][nf][r] + b1v[nf], 0.f) * w2v[nf];
    }

    // full 64-lane reduce: sums over cols (l16) and the wave's 32 rows
    psum += __shfl_xor(psum, 1, 64);
    psum += __shfl_xor(psum, 2, 64);
    psum += __shfl_xor(psum, 4, 64);
    psum += __shfl_xor(psum, 8, 64);
    psum += __shfl_xor(psum, 16, 64);
    psum += __shfl_xor(psum, 32, 64);
    if (lane == 0)
        atomicAdd(&out[blockIdx.y * 2 + (wave >> 1)], psum);
}

// ---------------------------------------------------------------------------
extern "C" void kernel_launch(void* const* d_in, const int* in_sizes, int n_in,
                              void* d_out, int out_size, void* d_ws, size_t ws_size,
                              hipStream_t stream)
{
    const float* init_state = (const float*)d_in[0];
    const float* choice_emb = (const float*)d_in[1];
    const int*   arg_seq    = (const int*)  d_in[2];
    const float* Wx         = (const float*)d_in[3];
    const float* Wh         = (const float*)d_in[4];
    const float* bg         = (const float*)d_in[5];
    const float* W1         = (const float*)d_in[6];
    const float* b1         = (const float*)d_in[7];
    const float* W2         = (const float*)d_in[8];
    const float* b2         = (const float*)d_in[9];
    float* out = (float*)d_out;

    // workspace layout
    ushort* WxT = (ushort*)d_ws;                 // [2048,512] bf16
    ushort* WhT = WxT + 1048576;                 // [2048,512] bf16
    ushort* W1T = WhT + 1048576;                 // [256,1024] bf16
    ushort* Xbf = W1T + 262144;                  // [BT,512]  bf16
    ushort* S   = Xbf + 8388608;                 // [B,T,H]   bf16
    ushort* h0  = S   + 8388608;                 // [B,H]
    ushort* pp0 = h0  + 131072;                  // [B,H]
    ushort* pp1 = pp0 + 131072;                  // [B,H]
    float*  scores  = (float*)(pp1 + 131072);    // [BT] (unused, kept for layout)
    int*    xcd_tbl = (int*)(scores + BT);       // [256]
    int*    cnts    = xcd_tbl + 256;             // [16 teams * 256] slot arrays

    // ONE prep launch: weights || gather || init || out-seed+sync-zero
    prep_all<<<PALL_N, 256, 0, stream>>>(
        Wx, Wh, W1, WxT, WhT, W1T,
        choice_emb, arg_seq, Xbf,
        init_state, h0, S,
        out, b2, xcd_tbl);

    // Phase A+B fused: persistent recurrence with in-kernel x@Wx
    lstm_fused_main<<<256, 512, 0, stream>>>(
        WhT, WxT, Xbf, bg, init_state, h0, pp0, pp1, S, xcd_tbl, cnts);

    // Phase C+D+reduce fused: one atomic per wave into out
    gemm_score<<<dim3(C1 / 64, BT / 128), 256, 0, stream>>>(
        S, Xbf, W1T, b1, W2, out);
}

// Round 13
// 370.261 us; speedup vs baseline: 1.2735x; 1.0135x over previous
//
#include <hip/hip_runtime.h>
#include <hip/hip_bf16.h>
#include <math.h>

// Problem constants
#define H   512
#define E   512
#define B_  256
#define T_  64
#define G4  2048   // 4*H
#define C1  256    // MLP hidden
#define BT  16384  // B*T

#define SPIN_CAP (1 << 22)   // discovery spin bound (dispatch latency)
#define POLL_CAP (1 << 18)   // per-step poll bound: failure -> slow-but-correct

typedef __attribute__((ext_vector_type(8))) short  short8;   // 8 bf16 (4 VGPRs)
typedef __attribute__((ext_vector_type(4))) float  f32x4;    // MFMA acc
typedef __attribute__((ext_vector_type(4))) int    i32x4;    // 16B granule
typedef __attribute__((ext_vector_type(4))) unsigned short ushort4v;
typedef unsigned short ushort;
typedef unsigned long long u64;

// LDS tile: row-major [row][kc granule], pitch 65 granules (odd) = 520 ushorts.
#define PITCH_US 520

#define BAR_LGKM() asm volatile("s_waitcnt lgkmcnt(0)\n\ts_barrier" ::: "memory")
#define BAR_ALL()  asm volatile("s_waitcnt vmcnt(0) lgkmcnt(0)\n\ts_barrier" ::: "memory")

// ---------------------------------------------------------------------------
// Design ledger (R0-R12, measured on MI355X):
//   - Cross-CU flags MUST go through the MALL (AGENT both sides). Local-L2
//     signaling impossible (R2/R3/R4). Streamed data: plain store -> same-XCD
//     consumer works (L2); cross-XCD needs agent store -> MALL (R0 h-path).
//   - Sync chain fully bracketed (R5/R7/R9 null/negative). Block-lockstep +
//     LDS staging + 2 waves/SIMD (R8) is the optimum; recurrence loop FROZEN.
//   - Same-line atomic RMWs convoy at high multiplicity (R11: 4096/line =
//     ~80us; R9/R12: <=256/line = free).
//   - R10: gemm n-fold regressed (parallelism-bound).
//   - R13 (this): gemm_score absorbed into lstm as a post-loop tail. Each
//     block scores its own team's 16 batches x its 4-t slice (same per-wave
//     workload as the R9 gemm). Sync: slot=64 after per-wave drain+barrier;
//     consumers poll team slots >= 64 then plain-load S (team-local L2 for
//     loc teams; MALL for non-loc whose S stores are agent-scope, mirroring
//     the h-store split). 16 atomicAdds/block (4096 total = cheap level).
//     Kernels: 3 -> 2; the 4x cross-die A re-read becomes 1x local.
// ---------------------------------------------------------------------------

__device__ __forceinline__ ushort f2bf(float x) {
    unsigned u = __builtin_bit_cast(unsigned, x);
    unsigned r = (u + 0x7FFFu + ((u >> 16) & 1u)) >> 16;
    return (ushort)r;
}
__device__ __forceinline__ float fast_sig(float x) {
    return __builtin_amdgcn_rcpf(1.f + __expf(-x));
}
__device__ __forceinline__ float fast_tanh(float x) {
    return 1.f - 2.f * __builtin_amdgcn_rcpf(1.f + __expf(2.f * x));
}

// 2x 16B loads, batched, drained. sc0: L1-bypass, local XCD L2 (R8-proven).
#define LOAD2_SC0(v0,v1,p0,p1) \
  asm volatile("global_load_dwordx4 %0, %2, off sc0\n\t" \
               "global_load_dwordx4 %1, %3, off sc0\n\t" \
               "s_waitcnt vmcnt(0)" \
               : "=&v"(v0), "=&v"(v1) : "v"(p0), "v"(p1) : "memory")
#define LOAD2_SC01(v0,v1,p0,p1) \
  asm volatile("global_load_dwordx4 %0, %2, off sc0 sc1\n\t" \
               "global_load_dwordx4 %1, %3, off sc0 sc1\n\t" \
               "s_waitcnt vmcnt(0)" \
               : "=&v"(v0), "=&v"(v1) : "v"(p0), "v"(p1) : "memory")

// ---------------------------------------------------------------------------
// P*: fused prep — ONE launch, grid-partitioned, all sections independent:
//   [0, 2304)          weight transpose+cast fp32 [K][N] -> bf16 [N][K]
//   [2304, 10496)      embed gather: 2 rows/block (128 thr each half)
//   [10496, 10624)     init_prep: 2 rows/block
//   [10624, 10642)     out[b] = T*b2 seed + zero xcd_tbl/cnts
// ---------------------------------------------------------------------------
#define PREP_N  2304
#define GATH_B  (PREP_N)
#define GATH_N  (BT / 2)
#define INIT_B  (GATH_B + GATH_N)
#define INIT_N  (B_ / 2)
#define ZERO_B  (INIT_B + INIT_N)
#define ZERO_N  18
#define PALL_N  (ZERO_B + ZERO_N)

__global__ __launch_bounds__(256) void prep_all(
    const float* __restrict__ Wx, const float* __restrict__ Wh,
    const float* __restrict__ W1,
    ushort* __restrict__ WxT, ushort* __restrict__ WhT, ushort* __restrict__ W1T,
    const float* __restrict__ emb, const int* __restrict__ idx,
    ushort* __restrict__ X,
    const float* __restrict__ init, ushort* __restrict__ h0,
    ushort* __restrict__ S,
    float* __restrict__ out, const float* __restrict__ b2,
    int* __restrict__ sync_ints)
{
    const int tid = threadIdx.x;
    int bx = blockIdx.x;

    if (bx < PREP_N) {
        // ---- weight transpose + cast ----
        __shared__ float t[32][33];
        const float* in; ushort* outp; int K, N, k0, n0;
        if (bx < 1024)       { in = Wx; outp = WxT; K = 512;  N = 2048; k0 = (bx >> 6) * 32; n0 = (bx & 63) * 32; }
        else if (bx < 2048)  { bx -= 1024; in = Wh; outp = WhT; K = 512;  N = 2048; k0 = (bx >> 6) * 32; n0 = (bx & 63) * 32; }
        else                 { bx -= 2048; in = W1; outp = W1T; K = 1024; N = 256;  k0 = (bx >> 3) * 32; n0 = (bx & 7) * 32; }
        const int tr = tid >> 3;
        const int tc = (tid & 7) * 4;
        float4 v = *(const float4*)(in + (size_t)(k0 + tr) * N + n0 + tc);
        t[tr][tc + 0] = v.x; t[tr][tc + 1] = v.y; t[tr][tc + 2] = v.z; t[tr][tc + 3] = v.w;
        __syncthreads();
        ushort4v o = { f2bf(t[tc + 0][tr]), f2bf(t[tc + 1][tr]),
                       f2bf(t[tc + 2][tr]), f2bf(t[tc + 3][tr]) };
        *(ushort4v*)(outp + (size_t)(n0 + tr) * K + k0 + tc) = o;
    } else if (bx < INIT_B) {
        // ---- embed gather: 2 rows per block ----
        const int r = (bx - GATH_B) * 2 + (tid >> 7);
        const int v = idx[r];
        const int c = (tid & 127) * 4;
        float4 f = *(const float4*)(emb + (size_t)v * E + c);
        ushort4v o = { f2bf(f.x), f2bf(f.y), f2bf(f.z), f2bf(f.w) };
        *(ushort4v*)(X + (size_t)r * E + c) = o;
    } else if (bx < ZERO_B) {
        // ---- init_prep: 2 rows per block ----
        const int r = (bx - INIT_B) * 2 + (tid >> 7);
        const int c = (tid & 127) * 4;
        float4 f = *(const float4*)(init + (size_t)r * H + c);
        ushort4v o = { f2bf(f.x), f2bf(f.y), f2bf(f.z), f2bf(f.w) };
        *(ushort4v*)(h0 + (size_t)r * H + c) = o;
        *(ushort4v*)(S + ((size_t)r * T_) * H + c) = o;
    } else {
        // ---- out seed + sync zero ----
        const int i = (bx - ZERO_B) * 256 + tid;
        if (i < 256) out[i] = (float)T_ * b2[0];
        else if (i < 256 + 256 + 4096) sync_ints[i - 256] = 0;
    }
}

// ---------------------------------------------------------------------------
// K2: persistent fused LSTM recurrence + fused x@Wx + post-loop score GEMM.
// Recurrence loop is the FROZEN R8/R9 form (256 blocks x 512 thr, 2 waves/
// SIMD, 16-block teams, slot-store sync). Post-loop: block (g,m) scores its
// team's 16 batches over t-slice m*4..m*4+3 (R13).
// ---------------------------------------------------------------------------
__global__ __launch_bounds__(512, 2) void lstm_fused_main(
    const ushort* __restrict__ WhT, const ushort* __restrict__ WxT,
    const ushort* __restrict__ Xbf, const float* __restrict__ bg,
    const float*  __restrict__ init_state, const ushort* __restrict__ h0,
    ushort* __restrict__ pp0, ushort* __restrict__ pp1,
    ushort* __restrict__ S, int* __restrict__ xcd_tbl, int* __restrict__ cnts,
    const ushort* __restrict__ W1T, const float* __restrict__ b1,
    const float* __restrict__ W2, float* __restrict__ out)
{
    __shared__ __align__(16) ushort hsh[16 * PITCH_US];
    __shared__ __align__(16) ushort xsh[2][16 * PITCH_US];
    __shared__ int exl[256];

    const int tid  = threadIdx.x;
    const int wave = tid >> 6, lane = tid & 63;
    const int quad = lane >> 4, l16 = lane & 15;

    // ---- one-time team discovery (bounded) ----
    int xcd;
    asm volatile("s_getreg_b32 %0, hwreg(HW_REG_XCC_ID)" : "=s"(xcd));
    if (tid == 0)
        __hip_atomic_store(&xcd_tbl[blockIdx.x], (xcd & 7) + 1,
                           __ATOMIC_RELAXED, __HIP_MEMORY_SCOPE_AGENT);
    if (wave == 0) {
        for (int it = 0; it < SPIN_CAP; ++it) {
            int miss = 0;
#pragma unroll
            for (int j = 0; j < 4; ++j) {
                int i = lane + j * 64;
                int v = __hip_atomic_load(&xcd_tbl[i], __ATOMIC_RELAXED,
                                          __HIP_MEMORY_SCOPE_AGENT);
                exl[i] = (v == 0) ? 0 : (v - 1);
                if (v == 0) miss = 1;
            }
            if (!__any(miss)) break;
            __builtin_amdgcn_s_sleep(4);
        }
    }
    BAR_LGKM();

    // deterministic assignment (identical scan in every thread)
    int g = 0, m = 0, loc = 0;
    {
        int cntx[8] = {0,0,0,0,0,0,0,0};
        for (int i = 0; i < 256; ++i) cntx[exl[i] & 7]++;
        int take[8], base[8], tA = 0;
        for (int x = 0; x < 8; ++x) {
            int tk = cntx[x] >> 4;
            if (tA + tk > 16) tk = 16 - tA;
            take[x] = tk; base[x] = tA; tA += tk;
        }
        int rc[8] = {0,0,0,0,0,0,0,0}, lc = 0;
        for (int i = 0; i < 256; ++i) {
            int x = exl[i] & 7, r = rc[x]++;
            if ((r >> 4) < take[x]) {
                if (i == (int)blockIdx.x) { g = base[x] + (r >> 4); m = r & 15; loc = 1; }
            } else {
                if (i == (int)blockIdx.x) { g = tA + (lc >> 4); m = lc & 15; loc = 0; }
                lc++;
            }
        }
    }

    const int n0    = g * 16;
    const int jw    = m * 32 + wave * 4;   // wave's 4 hidden-cols
    const int koff  = quad * 8;
    const int myrow = n0 + l16;
    const int hcol  = jw + quad;           // this thread's output hidden-col

    // A-frag preloads: one tile = 4 gates x 4 cols.
    short8 af[16], ax[16];
    {
        const size_t rowoff =
            (size_t)((l16 >> 2) * 512 + jw + (l16 & 3)) * 512 + koff;
        const ushort* bh = WhT + rowoff;
        const ushort* bx = WxT + rowoff;
#pragma unroll
        for (int kk = 0; kk < 16; ++kk) {
            af[kk] = *(const short8*)(bh + kk * 32);
            ax[kk] = *(const short8*)(bx + kk * 32);
        }
    }

    // bias: gate = quad, cols jw..jw+3 (added pre-transpose)
    float bgq[4];
#pragma unroll
    for (int r = 0; r < 4; ++r) bgq[r] = bg[quad * 512 + jw + r];

    // c-state: one (row, col) per thread
    float c1 = init_state[(size_t)myrow * H + hcol];

    // staging coords: 2 granules of 16B per thread (512 thr x 2 = 16x64)
    int gr[2], gc[2], lo[2];
#pragma unroll
    for (int j = 0; j < 2; ++j) {
        int lin = tid + j * 512;
        gr[j] = lin >> 6; gc[j] = lin & 63;
        lo[j] = gr[j] * PITCH_US + gc[j] * 8;
    }

    // stage x(0) into xsh[0]
#pragma unroll
    for (int j = 0; j < 2; ++j) {
        i32x4 v = *(const i32x4*)(Xbf + ((size_t)(n0 + gr[j]) * T_) * H + gc[j] * 8);
        *(i32x4*)&xsh[0][lo[j]] = v;
    }
    BAR_LGKM();

    // signal slots: 16 per team, 64B (16-int) stride (R9)
    int* slots = cnts + g * 256;              // 1KB apart per team
    int* myslot = slots + m * 16;
    const int* pollp = slots + (lane & 15) * 16;  // lane l -> slot l&15
    const int frag_base = l16 * PITCH_US + quad * 8;   // + kk*32

    for (int t = 0; t < T_ - 1; ++t) {
        // a) issue x(t+1) prefetch (plain cached loads)
        i32x4 xv0, xv1;
        const int have_x = (t + 1 < T_ - 1);
        if (have_x) {
            xv0 = *(const i32x4*)(Xbf + ((size_t)(n0 + gr[0]) * T_ + t + 1) * H + gc[0] * 8);
            xv1 = *(const i32x4*)(Xbf + ((size_t)(n0 + gr[1]) * T_ + t + 1) * H + gc[1] * 8);
        }

        // b) x-part MFMA (independent of h -> overlaps the wait)
        f32x4 axx = {};
        {
            const ushort* xb = xsh[t & 1];
#pragma unroll
            for (int kk = 0; kk < 16; ++kk) {
                short8 b = *(const short8*)&xb[frag_base + kk * 32];
                axx = __builtin_amdgcn_mfma_f32_16x16x32_bf16(ax[kk], b, axx, 0, 0, 0);
            }
        }

        // c) wait for teammates' h(t): lane-indexed slot poll, __all
        if (t > 0) {
            for (int it = 0; it < POLL_CAP; ++it) {
                int v = __hip_atomic_load(pollp, __ATOMIC_RELAXED,
                                          __HIP_MEMORY_SCOPE_AGENT);
                if (__all(v >= t)) break;
                __builtin_amdgcn_s_sleep(1);
            }
        }

        // d) stage h(t) into LDS (16B loads; local L2 for loc teams)
        {
            const ushort* hin = (t == 0) ? h0 : ((t & 1) ? pp0 : pp1);
            const ushort* p0 = hin + (size_t)(n0 + gr[0]) * H + gc[0] * 8;
            const ushort* p1 = hin + (size_t)(n0 + gr[1]) * H + gc[1] * 8;
            i32x4 v0, v1;
            if (loc) { LOAD2_SC0(v0, v1, p0, p1); }
            else     { LOAD2_SC01(v0, v1, p0, p1); }
            *(i32x4*)&hsh[lo[0]] = v0;
            *(i32x4*)&hsh[lo[1]] = v1;
        }
        BAR_LGKM();

        // e) h-part MFMA
        f32x4 ah = {};
#pragma unroll
        for (int kk = 0; kk < 16; ++kk) {
            short8 b = *(const short8*)&hsh[frag_base + kk * 32];
            ah = __builtin_amdgcn_mfma_f32_16x16x32_bf16(af[kk], b, ah, 0, 0, 0);
        }

        // f) write x(t+1) into the other xsh buffer
        if (have_x) {
            ushort* xb = xsh[(t + 1) & 1];
            *(i32x4*)&xb[lo[0]] = xv0;
            *(i32x4*)&xb[lo[1]] = xv1;
        }

        // g) epilogue. 4x4 quad-transpose (R8-verified mapping).
        float g4[4];
#pragma unroll
        for (int r = 0; r < 4; ++r) g4[r] = ah[r] + axx[r] + bgq[r];
        float s1 = (quad & 1) ? ((quad & 2) ? g4[2] : g4[0])
                              : ((quad & 2) ? g4[3] : g4[1]);
        float s2 = (quad & 2) ? ((quad & 1) ? g4[1] : g4[0])
                              : ((quad & 1) ? g4[3] : g4[2]);
        float s3 = (quad & 2) ? ((quad & 1) ? g4[0] : g4[1])
                              : ((quad & 1) ? g4[2] : g4[3]);
        float r0 = (quad & 1) ? ((quad & 2) ? g4[3] : g4[1])
                              : ((quad & 2) ? g4[2] : g4[0]);
        float r1 = __shfl_xor(s1, 16, 64);
        float r2 = __shfl_xor(s2, 32, 64);
        float r3 = __shfl_xor(s3, 48, 64);
        float iv = (quad == 0) ? r0 : (quad == 1) ? r1 : (quad == 2) ? r2 : r3;
        float fv = (quad == 0) ? r1 : (quad == 1) ? r0 : (quad == 2) ? r3 : r2;
        float gv = (quad == 0) ? r2 : (quad == 1) ? r3 : (quad == 2) ? r0 : r1;
        float ov = (quad == 0) ? r3 : (quad == 1) ? r2 : (quad == 2) ? r1 : r0;
        iv = fast_sig(iv);
        fv = fast_sig(fv);
        gv = fast_tanh(gv);
        ov = fast_sig(ov);
        float cn = fv * c1 + iv * gv;
        c1 = cn;
        ushort ho = f2bf(ov * fast_tanh(cn));

        // h) h store (exchange buffer): 2B per lane, every lane distinct
        ushort* hout = (t & 1) ? pp1 : pp0;
        {
            ushort* hp2 = hout + (size_t)myrow * H + hcol;
            if (loc) *hp2 = ho;
            else asm volatile("global_store_short %0, %1, off sc0 sc1"
                              :: "v"(hp2), "v"((int)ho) : "memory");
        }

        // i) drain h store, block barrier, then per-block slot STORE
        BAR_ALL();
        if (tid == 0)
            __hip_atomic_store(myslot, t + 1, __ATOMIC_RELAXED,
                               __HIP_MEMORY_SCOPE_AGENT);

        // j) S store AFTER the signal — drained by a later vmcnt(0).
        //    loc: plain (team-local L2 — tail consumers are on this XCD).
        //    non-loc: agent (MALL — tail consumers read via MALL miss).
        {
            ushort* sp = S + ((size_t)myrow * T_ + (t + 1)) * H + hcol;
            if (loc) *sp = ho;
            else __hip_atomic_store(sp, ho, __ATOMIC_RELAXED,
                                    __HIP_MEMORY_SCOPE_AGENT);
        }
    }

    // ======================================================================
    // R13 tail: score GEMM for team g's 16 batches, t-slice m*4..m*4+3.
    // Same per-wave workload as the proven R9 gemm_score (2 mf x 4 nf x
    // 32 K-chunks), A-rows remapped to (batch, t) pairs.
    // ======================================================================
    // 1) drain own S stores, block barrier, signal slot = T_ (64)
    asm volatile("s_waitcnt vmcnt(0)" ::: "memory");
    __syncthreads();
    if (tid == 0)
        __hip_atomic_store(myslot, T_, __ATOMIC_RELAXED,
                           __HIP_MEMORY_SCOPE_AGENT);
    // 2) wait for the whole team's S to be complete
    for (int it = 0; it < POLL_CAP; ++it) {
        int v = __hip_atomic_load(pollp, __ATOMIC_RELAXED,
                                  __HIP_MEMORY_SCOPE_AGENT);
        if (__all(v >= T_)) break;
        __builtin_amdgcn_s_sleep(1);
    }

    // 3) GEMM. wave -> (mhalf = wave>>2 : 32 of the 64 rows, nq = wave&3 :
    //    64 of the 256 units). Row index row16 = mhalf*32 + mf*16 + (load:
    //    l16 / output: quad*4+r); batch = row16>>2, t = ts + (row16&3).
    {
        const int mhalf = wave >> 2, nq = wave & 3;
        const int ts = m * 4;
        const int bl0 = mhalf * 8 + (l16 >> 2);       // batch of A-row (mf=0)
        const int tl  = l16 & 3;
        const size_t arow0 = ((size_t)(n0 + bl0) * T_ + ts + tl) * H + koff;
        const size_t arow1 = arow0 + (size_t)4 * T_ * H;   // mf=1: batch+4
        const ushort* a0pS = S   + arow0;
        const ushort* a1pS = S   + arow1;
        const ushort* a0pX = Xbf + arow0;
        const ushort* a1pX = Xbf + arow1;

        f32x4 acc[2][4] = {};
        for (int src = 0; src < 2; ++src) {
            const ushort* a0p = src ? a0pX : a0pS;
            const ushort* a1p = src ? a1pX : a1pS;
            const ushort* bp  = W1T + src * 512
                              + (size_t)(nq * 64 + l16) * 1024 + koff;
            for (int kk = 0; kk < H; kk += 32) {
                short8 a0 = *(const short8*)(a0p + kk);
                short8 a1 = *(const short8*)(a1p + kk);
#pragma unroll
                for (int nf = 0; nf < 4; ++nf) {
                    short8 b = *(const short8*)(bp + (size_t)nf * 16 * 1024 + kk);
                    acc[0][nf] = __builtin_amdgcn_mfma_f32_16x16x32_bf16(a0, b, acc[0][nf], 0, 0, 0);
                    acc[1][nf] = __builtin_amdgcn_mfma_f32_16x16x32_bf16(a1, b, acc[1][nf], 0, 0, 0);
                }
            }
        }

        float w2v[4], b1v[4];
#pragma unroll
        for (int nf = 0; nf < 4; ++nf) {
            const int col = nq * 64 + nf * 16 + l16;
            w2v[nf] = W2[col];
            b1v[nf] = b1[col];
        }

        // fold: relu per (row,unit) -> dot W2 -> sum over r (4 t's of one
        // batch: row16 = mhalf*32+mf*16+quad*4+r => batch mhalf*8+mf*4+quad)
        // -> l16 shfl-reduce (16 units) -> LDS partial per (wave, mf, quad).
        float* red = (float*)exl;   // 64 floats, exl is free post-loop
#pragma unroll
        for (int mf = 0; mf < 2; ++mf) {
            float q = 0.f;
#pragma unroll
            for (int r = 0; r < 4; ++r)
#pragma unroll
                for (int nf = 0; nf < 4; ++nf)
                    q += fmaxf(acc[mf][nf][r] + b1v[nf], 0.f) * w2v[nf];
            q += __shfl_xor(q, 1, 64);
            q += __shfl_xor(q, 2, 64);
            q += __shfl_xor(q, 4, 64);
            q += __shfl_xor(q, 8, 64);
            if (l16 == 0) red[wave * 8 + mf * 4 + quad] = q;
        }
    }
    __syncthreads();

    // 4) final: batch bl -> partials at waves mhalf*4+nq; 16 atomics/block
    if (wave == 0 && lane < 16) {
        const float* red = (const float*)exl;
        const int mh = lane >> 3, mf = (lane >> 2) & 1, qd = lane & 3;
        float s = 0.f;
#pragma unroll
        for (int nq = 0; nq < 4; ++nq)
            s += red[(mh * 4 + nq) * 8 + mf * 4 + qd];
        atomicAdd(&out[n0 + lane], s);
    }
}

// ---------------------------------------------------------------------------
extern "C" void kernel_launch(void* const* d_in, const int* in_sizes, int n_in,
                              void* d_out, int out_size, void* d_ws, size_t ws_size,
                              hipStream_t stream)
{
    const float* init_state = (const float*)d_in[0];
    const float* choice_emb = (const float*)d_in[1];
    const int*   arg_seq    = (const int*)  d_in[2];
    const float* Wx         = (const float*)d_in[3];
    const float* Wh         = (const float*)d_in[4];
    const float* bg         = (const float*)d_in[5];
    const float* W1         = (const float*)d_in[6];
    const float* b1         = (const float*)d_in[7];
    const float* W2         = (const float*)d_in[8];
    const float* b2         = (const float*)d_in[9];
    float* out = (float*)d_out;

    // workspace layout
    ushort* WxT = (ushort*)d_ws;                 // [2048,512] bf16
    ushort* WhT = WxT + 1048576;                 // [2048,512] bf16
    ushort* W1T = WhT + 1048576;                 // [256,1024] bf16
    ushort* Xbf = W1T + 262144;                  // [BT,512]  bf16
    ushort* S   = Xbf + 8388608;                 // [B,T,H]   bf16
    ushort* h0  = S   + 8388608;                 // [B,H]
    ushort* pp0 = h0  + 131072;                  // [B,H]
    ushort* pp1 = pp0 + 131072;                  // [B,H]
    float*  scores  = (float*)(pp1 + 131072);    // [BT] (unused, kept for layout)
    int*    xcd_tbl = (int*)(scores + BT);       // [256]
    int*    cnts    = xcd_tbl + 256;             // [16 teams * 256] slot arrays

    // ONE prep launch: weights || gather || init || out-seed+sync-zero
    prep_all<<<PALL_N, 256, 0, stream>>>(
        Wx, Wh, W1, WxT, WhT, W1T,
        choice_emb, arg_seq, Xbf,
        init_state, h0, S,
        out, b2, xcd_tbl);

    // Phase A+B+C+D fused: recurrence + in-kernel x@Wx + post-loop score
    lstm_fused_main<<<256, 512, 0, stream>>>(
        WhT, WxT, Xbf, bg, init_state, h0, pp0, pp1, S, xcd_tbl, cnts,
        W1T, b1, W2, out);
}